// Round 1
// baseline (563.697 us; speedup 1.0000x reference)
//
#include <hip/hip_runtime.h>
#include <hip/hip_bf16.h>

typedef __attribute__((ext_vector_type(4))) float f32x4;
typedef __attribute__((ext_vector_type(8))) short bf16x8;

#define S_LEN 1024
#define D_DIM 64
#define QT    32
#define KT    128
#define NKVT  (S_LEN / KT)

__device__ __forceinline__ unsigned short bf16u(float x) {
    union { float f; unsigned u; } v; v.f = x;
    return (unsigned short)((v.u + 0x7fffu + ((v.u >> 16) & 1u)) >> 16);
}

__device__ __forceinline__ bf16x8 ld_frag(const unsigned short* base) {
    // fragment elements {0..3} at base, {4..7} at base+16 (two x16 halves)
    union { bf16x8 v; unsigned long long u[2]; } r;
    r.u[0] = *(const unsigned long long*)(base);
    r.u[1] = *(const unsigned long long*)(base + 16);
    return r.v;
}

__global__ __launch_bounds__(512) void attn_fused(
    const float* __restrict__ Qg, const float* __restrict__ Kg,
    const float* __restrict__ Vg, const int* __restrict__ Mg,
    float* __restrict__ Og, float* __restrict__ Ag)
{
    const int tid  = threadIdx.x;
    const int lane = tid & 63;
    const int wid  = tid >> 6;
    const int l15  = lane & 15;
    const int lg   = lane >> 4;   // 0..3
    const int wr   = wid >> 2;    // 0..1  (q half)
    const int wc   = wid & 3;     // 0..3  (col strip in P1, d strip in P2)

    const int bid = blockIdx.x;
    const int bh  = bid >> 5;     // 0..127
    const int qt  = bid & 31;     // 0..31
    const int b   = bh >> 4;

    const size_t kvbase = (size_t)bh * (S_LEN * D_DIM);
    const float* Qp = Qg + kvbase + (size_t)qt * (QT * D_DIM);
    const float* Kp = Kg + kvbase;
    const float* Vp = Vg + kvbase;
    const int*   Mp = Mg + (size_t)b * (size_t)(S_LEN * S_LEN) + (size_t)(qt * QT) * S_LEN;
    float*       Ap = Ag + (size_t)bh * (size_t)(S_LEN * S_LEN) + (size_t)(qt * QT) * S_LEN;
    float*       Op = Og + kvbase + (size_t)qt * (QT * D_DIM);

    __shared__ unsigned short Qs[QT][D_DIM + 8];     // 32x72 bf16
    __shared__ unsigned short Ks[KT][D_DIM + 8];     // 128x72
    __shared__ unsigned short Vt[D_DIM][KT + 8];     // 64x136 (V transposed, d-major)
    __shared__ unsigned short Ps[QT][KT + 8];        // 32x136
    __shared__ float red[2][16][4];

    // ---- Q tile -> LDS (bf16), one float4 per thread ----
    {
        const float4 q4 = *(const float4*)(Qp + tid * 4);
        const int row = tid >> 4, col = (tid & 15) * 4;
        Qs[row][col + 0] = bf16u(q4.x);
        Qs[row][col + 1] = bf16u(q4.y);
        Qs[row][col + 2] = bf16u(q4.z);
        Qs[row][col + 3] = bf16u(q4.w);
    }
    __syncthreads();

    // A fragments (Q rows wr*16..+15), cached for all of phase 1
    bf16x8 aq[2];
    {
        const unsigned short* qrow = &Qs[wr * 16 + l15][0];
        const int kb = lg * 4;
        aq[0] = ld_frag(qrow + kb);
        aq[1] = ld_frag(qrow + 32 + kb);
    }

    f32x4 sc[16];
#pragma unroll
    for (int t = 0; t < 16; ++t) sc[t] = (f32x4){0.f, 0.f, 0.f, 0.f};

    // ---- Phase 1: scores = Q K^T ----
    for (int kvt = 0; kvt < NKVT; ++kvt) {
        __syncthreads();
#pragma unroll
        for (int i = 0; i < 4; ++i) {
            const int f = (i * 512 + tid) * 4;
            const int row = f >> 6, col = f & 63;
            const float4 k4 = *(const float4*)(Kp + (size_t)kvt * (KT * D_DIM) + f);
            Ks[row][col + 0] = bf16u(k4.x);
            Ks[row][col + 1] = bf16u(k4.y);
            Ks[row][col + 2] = bf16u(k4.z);
            Ks[row][col + 3] = bf16u(k4.w);
        }
        __syncthreads();
        const int kb = lg * 4;
#pragma unroll
        for (int ct = 0; ct < 2; ++ct) {
            const unsigned short* krow = &Ks[wc * 32 + ct * 16 + l15][0];
            bf16x8 bk0 = ld_frag(krow + kb);
            bf16x8 bk1 = ld_frag(krow + 32 + kb);
            f32x4 acc = sc[kvt * 2 + ct];
            acc = __builtin_amdgcn_mfma_f32_16x16x32_bf16(aq[0], bk0, acc, 0, 0, 0);
            acc = __builtin_amdgcn_mfma_f32_16x16x32_bf16(aq[1], bk1, acc, 0, 0, 0);
            sc[kvt * 2 + ct] = acc;
        }
    }

    // ---- scale + mask (masked -> 1e-9, faithful to reference) ----
    const int qrow0 = wr * 16 + lg * 4;   // + r gives local q row
#pragma unroll
    for (int t = 0; t < 16; ++t) {
        const int colg = (t >> 1) * KT + wc * 32 + (t & 1) * 16 + l15;
#pragma unroll
        for (int r = 0; r < 4; ++r) {
            const float s = sc[t][r] * 0.125f;
            const int mm = Mp[(size_t)(qrow0 + r) * S_LEN + colg];
            sc[t][r] = mm ? 1e-9f : s;
        }
    }

    // ---- row max (intra-wave shuffle over 16 lanes, then cross-wave via LDS) ----
    float rmax[4];
#pragma unroll
    for (int r = 0; r < 4; ++r) {
        float m = sc[0][r];
#pragma unroll
        for (int t = 1; t < 16; ++t) m = fmaxf(m, sc[t][r]);
        rmax[r] = m;
    }
#pragma unroll
    for (int sh = 1; sh <= 8; sh <<= 1)
#pragma unroll
        for (int r = 0; r < 4; ++r)
            rmax[r] = fmaxf(rmax[r], __shfl_xor(rmax[r], sh));
    __syncthreads();
    if (l15 == 0) {
#pragma unroll
        for (int r = 0; r < 4; ++r) red[wr][lg * 4 + r][wc] = rmax[r];
    }
    __syncthreads();
#pragma unroll
    for (int r = 0; r < 4; ++r) {
        const float* q = red[wr][lg * 4 + r];
        rmax[r] = fmaxf(fmaxf(q[0], q[1]), fmaxf(q[2], q[3]));
    }

    // ---- exp + row sum ----
    float rsum[4] = {0.f, 0.f, 0.f, 0.f};
#pragma unroll
    for (int t = 0; t < 16; ++t)
#pragma unroll
        for (int r = 0; r < 4; ++r) {
            const float p = __expf(sc[t][r] - rmax[r]);
            sc[t][r] = p;
            rsum[r] += p;
        }
#pragma unroll
    for (int sh = 1; sh <= 8; sh <<= 1)
#pragma unroll
        for (int r = 0; r < 4; ++r)
            rsum[r] += __shfl_xor(rsum[r], sh);
    __syncthreads();   // all rmax reads of red complete
    if (l15 == 0) {
#pragma unroll
        for (int r = 0; r < 4; ++r) red[wr][lg * 4 + r][wc] = rsum[r];
    }
    __syncthreads();
    float rinv[4];
#pragma unroll
    for (int r = 0; r < 4; ++r) {
        const float* q = red[wr][lg * 4 + r];
        rinv[r] = 1.0f / (q[0] + q[1] + q[2] + q[3]);
    }
#pragma unroll
    for (int t = 0; t < 16; ++t)
#pragma unroll
        for (int r = 0; r < 4; ++r)
            sc[t][r] *= rinv[r];

    // ---- Phase 2: attn write + context = P V ----
    f32x4 co = (f32x4){0.f, 0.f, 0.f, 0.f};
    for (int kvt = 0; kvt < NKVT; ++kvt) {
        __syncthreads();   // previous iteration's Ps/Vt reads done
#pragma unroll
        for (int ct = 0; ct < 2; ++ct) {
            const int t = kvt * 2 + ct;
            const int col_l = wc * 32 + ct * 16 + l15;
#pragma unroll
            for (int r = 0; r < 4; ++r) {
                const float p = sc[t][r];
                Ap[(size_t)(qrow0 + r) * S_LEN + kvt * KT + col_l] = p;
                Ps[wr * 16 + lg * 4 + r][col_l] = bf16u(p);
            }
        }
        {
            const int c  = tid >> 2;    // 0..127 (kv row within tile)
            const int dg = tid & 3;     // 16-d group
            const float* vsrc = Vp + (size_t)(kvt * KT + c) * D_DIM + dg * 16;
#pragma unroll
            for (int i = 0; i < 4; ++i) {
                const float4 v4 = *(const float4*)(vsrc + i * 4);
                const int d0 = dg * 16 + i * 4;
                Vt[d0 + 0][c] = bf16u(v4.x);
                Vt[d0 + 1][c] = bf16u(v4.y);
                Vt[d0 + 2][c] = bf16u(v4.z);
                Vt[d0 + 3][c] = bf16u(v4.w);
            }
        }
        __syncthreads();
        const unsigned short* prow = &Ps[wr * 16 + l15][0];
        const unsigned short* vrow = &Vt[wc * 16 + l15][0];
        const int kb = lg * 4;
#pragma unroll
        for (int m = 0; m < 4; ++m) {
            bf16x8 ap = ld_frag(prow + m * 32 + kb);
            bf16x8 bv = ld_frag(vrow + m * 32 + kb);
            co = __builtin_amdgcn_mfma_f32_16x16x32_bf16(ap, bv, co, 0, 0, 0);
        }
    }

#pragma unroll
    for (int r = 0; r < 4; ++r)
        Op[(size_t)(qrow0 + r) * D_DIM + wc * 16 + l15] = co[r];
}

extern "C" void kernel_launch(void* const* d_in, const int* in_sizes, int n_in,
                              void* d_out, int out_size, void* d_ws, size_t ws_size,
                              hipStream_t stream) {
    const float* Q = (const float*)d_in[0];
    const float* K = (const float*)d_in[1];
    const float* V = (const float*)d_in[2];
    const int*   M = (const int*)d_in[3];
    float* ctx  = (float*)d_out;
    float* attn = ctx + (size_t)8 * 16 * 1024 * 64;   // context first, then attn
    attn_fused<<<dim3(4096), dim3(512), 0, stream>>>(Q, K, V, M, ctx, attn);
}